// Round 9
// baseline (364.282 us; speedup 1.0000x reference)
//
#include <hip/hip_runtime.h>
#include <hip/hip_bf16.h>
#include <cstdint>

#define D_DIM 768
#define BM 128
#define BN 256
#define BK 64                   // K-tile = one K=64 MFMA step; 12 tiles

typedef int   intx8    __attribute__((ext_vector_type(8)));
typedef float floatx16 __attribute__((ext_vector_type(16)));

#define SCALE_ONE 0x7F7F7F7F  // E8M0 127 = 2^0 in every byte

// ---- helpers ----------------------------------------------------------------

__device__ inline void lds_load16(const void* g, void* lds) {
  __builtin_amdgcn_global_load_lds(
      (const __attribute__((address_space(1))) unsigned int*)g,
      (__attribute__((address_space(3))) unsigned int*)lds,
      16, 0, 0);
}

// two 16-B LDS reads at swizzled chunk offsets o0/o1 within a 64-B row
__device__ inline intx8 ldfrag2(const unsigned char* p, int o0, int o1) {
  intx8 r;
  *(int4*)&r       = *(const int4*)(p + o0);
  *((int4*)&r + 1) = *(const int4*)(p + o1);
  return r;
}

// ---- kernel 1: row L2 norm + normalize + cast to fp8 e4m3 (both inputs) -----

__global__ __launch_bounds__(256) void norm_cast_kernel(
    const float* __restrict__ EX, const float* __restrict__ EY,
    unsigned int* __restrict__ XO, unsigned int* __restrict__ YO, int Nx) {
  int row = blockIdx.x * 4 + (threadIdx.x >> 6);
  int lane = threadIdx.x & 63;
  const float* X = (row < Nx) ? EX : EY;
  unsigned int* Y = (row < Nx) ? XO : YO;
  int r = (row < Nx) ? row : (row - Nx);
  const float4* xr = (const float4*)(X + (size_t)r * D_DIM);
  float4 a = xr[lane];
  float4 b = xr[lane + 64];
  float4 c = xr[lane + 128];
  float ss = a.x*a.x + a.y*a.y + a.z*a.z + a.w*a.w
           + b.x*b.x + b.y*b.y + b.z*b.z + b.w*b.w
           + c.x*c.x + c.y*c.y + c.z*c.z + c.w*c.w;
  #pragma unroll
  for (int off = 32; off > 0; off >>= 1) ss += __shfl_xor(ss, off, 64);
  float s = 1.0f / fmaxf(sqrtf(ss), 1e-8f);
  unsigned int* yr = Y + (size_t)r * (D_DIM / 4);
  int d;
  d = __builtin_amdgcn_cvt_pk_fp8_f32(a.x * s, a.y * s, 0, false);
  d = __builtin_amdgcn_cvt_pk_fp8_f32(a.z * s, a.w * s, d, true);
  yr[lane] = (unsigned int)d;
  d = __builtin_amdgcn_cvt_pk_fp8_f32(b.x * s, b.y * s, 0, false);
  d = __builtin_amdgcn_cvt_pk_fp8_f32(b.z * s, b.w * s, d, true);
  yr[lane + 64] = (unsigned int)d;
  d = __builtin_amdgcn_cvt_pk_fp8_f32(c.x * s, c.y * s, 0, false);
  d = __builtin_amdgcn_cvt_pk_fp8_f32(c.z * s, c.w * s, d, true);
  yr[lane + 128] = (unsigned int)d;
}

// ---- kernel 2: MX-fp8 MFMA GEMM (S = A . B^T) fused with per-row max --------
// R8 no-spill skeleton (unroll-1 outer loop, 2 static-parity halves, += ptr
// bumps, over-prefetch into dead buffer) + R2-verified read swizzle:
// 64-B LDS rows, phys 16B-chunk = j ^ ((row>>1)&3). Deposit lane covers
// row lane>>2, phys chunk lane&3 -> fetches global chunk
// (lane&3)^((lane>>3)&3). Reader XORs chunk offsets with (l31>>1)&3 ->
// every 8-lane phase of a ds_read_b128 covers all 32 banks.
// R8 measured: un-swizzled reads cost 7.7 cyc/instr of conflicts (1.8e7).

#define HALF_TILE(RA, RB, LA, LB, GOFF)                                        \
  {                                                                            \
    intx8 a0 = ldfrag2(RA, o0, o1);                                            \
    intx8 a1 = ldfrag2(RA + 32 * BK, o0, o1);                                  \
    intx8 b0 = ldfrag2(RB, o0, o1);                                            \
    intx8 b1 = ldfrag2(RB + 32 * BK, o0, o1);                                  \
    intx8 b2 = ldfrag2(RB + 64 * BK, o0, o1);                                  \
    intx8 b3 = ldfrag2(RB + 96 * BK, o0, o1);                                  \
    lds_load16(gA + (GOFF), LA);                                               \
    lds_load16(gA + (GOFF) + g16, LA + 1024);                                  \
    lds_load16(gB + (GOFF), LB);                                               \
    lds_load16(gB + (GOFF) + g16, LB + 1024);                                  \
    lds_load16(gB + (GOFF) + 2 * g16, LB + 2048);                              \
    lds_load16(gB + (GOFF) + 3 * g16, LB + 3072);                              \
    acc[0][0] = __builtin_amdgcn_mfma_scale_f32_32x32x64_f8f6f4(               \
        a0, b0, acc[0][0], 0, 0, 0, SCALE_ONE, 0, SCALE_ONE);                  \
    acc[1][0] = __builtin_amdgcn_mfma_scale_f32_32x32x64_f8f6f4(               \
        a1, b0, acc[1][0], 0, 0, 0, SCALE_ONE, 0, SCALE_ONE);                  \
    acc[0][1] = __builtin_amdgcn_mfma_scale_f32_32x32x64_f8f6f4(               \
        a0, b1, acc[0][1], 0, 0, 0, SCALE_ONE, 0, SCALE_ONE);                  \
    acc[1][1] = __builtin_amdgcn_mfma_scale_f32_32x32x64_f8f6f4(               \
        a1, b1, acc[1][1], 0, 0, 0, SCALE_ONE, 0, SCALE_ONE);                  \
    acc[0][2] = __builtin_amdgcn_mfma_scale_f32_32x32x64_f8f6f4(               \
        a0, b2, acc[0][2], 0, 0, 0, SCALE_ONE, 0, SCALE_ONE);                  \
    acc[1][2] = __builtin_amdgcn_mfma_scale_f32_32x32x64_f8f6f4(               \
        a1, b2, acc[1][2], 0, 0, 0, SCALE_ONE, 0, SCALE_ONE);                  \
    acc[0][3] = __builtin_amdgcn_mfma_scale_f32_32x32x64_f8f6f4(               \
        a0, b3, acc[0][3], 0, 0, 0, SCALE_ONE, 0, SCALE_ONE);                  \
    acc[1][3] = __builtin_amdgcn_mfma_scale_f32_32x32x64_f8f6f4(               \
        a1, b3, acc[1][3], 0, 0, 0, SCALE_ONE, 0, SCALE_ONE);                  \
    __syncthreads();                                                           \
  }

__global__ __launch_bounds__(256, 2) void gemm_max_kernel(
    const unsigned char* __restrict__ A,   // exn [Nx][768] fp8 row-major
    const unsigned char* __restrict__ B,   // eyn [Ny][768] fp8 row-major
    float* __restrict__ partial,           // [ncb][Nx]
    int Nx) {
  __shared__ unsigned char As[2 * BM * BK];  // 2 x 8 KB
  __shared__ unsigned char Bs[2 * BN * BK];  // 2 x 16 KB
  __shared__ float red[2][BM];

  const int tid  = threadIdx.x;
  const int wave = tid >> 6;
  const int lane = tid & 63;
  const int wm = wave >> 1;        // 0..1: row half (64 rows)
  const int wn = wave & 1;         // 0..1: col half (128 cols)
  const int l31 = lane & 31;
  const int h   = lane >> 5;

  // read-side swizzled chunk offsets (row-invariant per lane)
  const int skey = (l31 >> 1) & 3;
  const int o0 = ((2 * h)     ^ skey) * 16;
  const int o1 = ((2 * h + 1) ^ skey) * 16;

  floatx16 acc[2][4];
  #pragma unroll
  for (int mt = 0; mt < 2; ++mt)
    #pragma unroll
    for (int nt = 0; nt < 4; ++nt)
      acc[mt][nt] = (floatx16)(0.f);

  // staging: instr covers 16 rows x 64 B; lane -> row lane>>2,
  // phys chunk lane&3 -> global chunk (lane&3)^((lane>>3)&3)
  const int srow = lane >> 2;
  const int schk = ((lane & 3) ^ ((lane >> 3) & 3)) * 16;
  const unsigned char* gA =
      A + (size_t)(blockIdx.x * BM + wave * 32 + srow) * D_DIM + schk;
  const unsigned char* gB =
      B + (size_t)(blockIdx.y * BN + wave * 64 + srow) * D_DIM + schk;
  const size_t g16 = (size_t)16 * D_DIM;
  unsigned char* lA0 = As + (size_t)(wave * 32) * BK;   // buf0 deposit base
  unsigned char* lA1 = lA0 + BM * BK;
  unsigned char* lB0 = Bs + (size_t)(wave * 64) * BK;
  unsigned char* lB1 = lB0 + BN * BK;

  // fragment read row bases (buf0; buf1 = + BM*BK / + BN*BK)
  const unsigned char* rA = As + (size_t)(wm * 64 + l31) * BK;
  const unsigned char* rB = Bs + (size_t)(wn * 128 + l31) * BK;

  // prologue: stage tile 0 into buffer 0
  lds_load16(gA, lA0);
  lds_load16(gA + g16, lA0 + 1024);
  #pragma unroll
  for (int i = 0; i < 4; ++i) lds_load16(gB + i * g16, lB0 + i * 1024);
  __syncthreads();

  #pragma unroll 1
  for (int it = 0; it < 6; ++it) {
    // tile 2it: read buf0, stage tile 2it+1 -> buf1
    HALF_TILE(rA, rB, lA1, lB1, 64)
    // tile 2it+1: read buf1, stage tile 2it+2 -> buf0 (last over-prefetches
    // into dead space; stays inside d_ws)
    HALF_TILE(rA + BM * BK, rB + BN * BK, lA0, lB0, 128)
    gA += 128;
    gB += 128;
  }

  // epilogue: per-row max over this block's 256 columns.
  // C/D (32x32): col = l31 (+nt*32 + wn*128), row = (reg&3)+8*(reg>>2)+4*h (+mt*32+wm*64)
  #pragma unroll
  for (int mt = 0; mt < 2; ++mt) {
    #pragma unroll
    for (int reg = 0; reg < 16; ++reg) {
      float v = fmaxf(fmaxf(acc[mt][0][reg], acc[mt][1][reg]),
                      fmaxf(acc[mt][2][reg], acc[mt][3][reg]));
      #pragma unroll
      for (int off = 1; off < 32; off <<= 1)
        v = fmaxf(v, __shfl_xor(v, off, 64));
      if (l31 == 0) {
        int r = wm * 64 + mt * 32 + (reg & 3) + 8 * (reg >> 2) + 4 * h;
        red[wn][r] = v;
      }
    }
  }
  __syncthreads();
  if (tid < BM) {
    float m = fmaxf(red[0][tid], red[1][tid]);
    partial[(size_t)blockIdx.y * Nx + blockIdx.x * BM + tid] = m;
  }
}

// ---- kernel 3: fused row-max over column blocks + transform + total sum -----
// single block (saves a launch; partial is 2 MB, L2-resident)

__global__ __launch_bounds__(1024) void finalize_kernel(
    const float* __restrict__ partial, float* __restrict__ out, int Nx, int ncb) {
  __shared__ float sdata[16];
  const float logc = -0.22579135264472744f;  // 0.5*log(2/pi), sigma=1
  float t = 0.f;
  for (int r = threadIdx.x; r < Nx; r += 1024) {
    float m = -1e30f;
    for (int cb = 0; cb < ncb; ++cb)
      m = fmaxf(m, partial[(size_t)cb * Nx + r]);
    float x = 1.0f - m;
    float l = logc - 0.5f * x * x;
    t += -__expf(l) * l;
  }
  #pragma unroll
  for (int off = 32; off > 0; off >>= 1) t += __shfl_xor(t, off, 64);
  int wv = threadIdx.x >> 6;
  if ((threadIdx.x & 63) == 0) sdata[wv] = t;
  __syncthreads();
  if (threadIdx.x == 0) {
    float s = 0.f;
    #pragma unroll
    for (int w = 0; w < 16; ++w) s += sdata[w];
    out[0] = s;
    out[1] = s;
  }
}

// ---- launch -----------------------------------------------------------------

extern "C" void kernel_launch(void* const* d_in, const int* in_sizes, int n_in,
                              void* d_out, int out_size, void* d_ws, size_t ws_size,
                              hipStream_t stream) {
  const float* ex = (const float*)d_in[0];
  const float* ey = (const float*)d_in[1];
  const int Nx = in_sizes[0] / D_DIM;   // 8192
  const int Ny = in_sizes[1] / D_DIM;   // 16384
  const int ncb = Ny / BN;              // 64

  char* ws = (char*)d_ws;
  unsigned char* exn = (unsigned char*)ws;                 // Nx*768 fp8
  unsigned char* eyn = exn + (size_t)Nx * D_DIM;           // Ny*768 fp8
  float* partial = (float*)(eyn + (size_t)Ny * D_DIM);     // ncb*Nx f32 (also
                                                           // absorbs over-prefetch)
  norm_cast_kernel<<<(Nx + Ny) / 4, 256, 0, stream>>>(
      ex, ey, (unsigned int*)exn, (unsigned int*)eyn, Nx);
  gemm_max_kernel<<<dim3(Nx / BM, Ny / BN), 256, 0, stream>>>(exn, eyn, partial, Nx);
  finalize_kernel<<<1, 1024, 0, stream>>>(partial, (float*)d_out, Nx, ncb);
}